// Round 2
// baseline (2321.945 us; speedup 1.0000x reference)
//
#include <hip/hip_runtime.h>

#define N_NODES 32768
#define M_EDGES 8192
#define IN_DIM  256
#define OUT_F   64

#define KC1 16   // GEMM1 K-split chunks (n-dim)
#define KC2 4    // GEMM2 K-split chunks (m-dim)

typedef __attribute__((ext_vector_type(8))) short  bf16x8;
typedef __attribute__((ext_vector_type(4))) float  f32x4;

__device__ __forceinline__ unsigned short f2bf_rne(float f) {
    unsigned u = __float_as_uint(f);
    unsigned r = (u + 0x7FFFu + ((u >> 16) & 1u)) >> 16;
    return (unsigned short)r;
}
__device__ __forceinline__ float bf2f(unsigned short h) {
    return __uint_as_float(((unsigned)h) << 16);
}

// ---------------------------------------------------------------------------
// k_prep: stream H fp32 once. Emits HT (bf16, exact: H is 0/1), Dv partials
// (atomic), De partials (LDS-reduced atomic). Tile [256 n x 128 m].
// ---------------------------------------------------------------------------
__global__ __launch_bounds__(256) void k_prep(const float* __restrict__ H,
                                              const float* __restrict__ w,
                                              unsigned short* __restrict__ HT,
                                              float* __restrict__ Dv_raw,
                                              float* __restrict__ De) {
    __shared__ unsigned short ht_s[128][264];   // 66 KB, padded
    __shared__ float w_s[128];
    __shared__ float de_s[128];
    int t = threadIdx.x;
    int n0 = blockIdx.x * 256;
    int m0 = blockIdx.y * 128;
    if (t < 128) { w_s[t] = w[m0 + t]; de_s[t] = 0.f; }
    __syncthreads();

    int c  = t & 31;          // float4 column within 128-wide tile
    int rp = t >> 5;          // row phase 0..7
    float de0 = 0.f, de1 = 0.f, de2 = 0.f, de3 = 0.f;
    for (int it = 0; it < 32; ++it) {
        int r = it * 8 + rp;                       // 0..255
        float4 hv = ((const float4*)(H + (size_t)(n0 + r) * M_EDGES + m0))[c];
        int mb = 4 * c;
        ht_s[mb + 0][r] = (unsigned short)(__float_as_uint(hv.x) >> 16);
        ht_s[mb + 1][r] = (unsigned short)(__float_as_uint(hv.y) >> 16);
        ht_s[mb + 2][r] = (unsigned short)(__float_as_uint(hv.z) >> 16);
        ht_s[mb + 3][r] = (unsigned short)(__float_as_uint(hv.w) >> 16);
        float dp = hv.x * w_s[mb] + hv.y * w_s[mb + 1]
                 + hv.z * w_s[mb + 2] + hv.w * w_s[mb + 3];
        dp += __shfl_xor(dp, 1, 64);  dp += __shfl_xor(dp, 2, 64);
        dp += __shfl_xor(dp, 4, 64);  dp += __shfl_xor(dp, 8, 64);
        dp += __shfl_xor(dp, 16, 64);
        if ((t & 31) == 0) atomicAdd(&Dv_raw[n0 + r], dp);
        de0 += hv.x; de1 += hv.y; de2 += hv.z; de3 += hv.w;
    }
    atomicAdd(&de_s[4 * c + 0], de0);
    atomicAdd(&de_s[4 * c + 1], de1);
    atomicAdd(&de_s[4 * c + 2], de2);
    atomicAdd(&de_s[4 * c + 3], de3);
    __syncthreads();
    if (t < 128) atomicAdd(&De[m0 + t], de_s[t]);

    // write-out: HT rows, 512 B contiguous per row
    int lane = t & 63, wv = t >> 6;
    for (int i = 0; i < 32; ++i) {
        int ml = wv * 32 + i;
        ushort4 v = *(const ushort4*)&ht_s[ml][lane * 4];
        *(ushort4*)(HT + (size_t)(m0 + ml) * N_NODES + n0 + lane * 4) = v;
    }
}

// ---------------------------------------------------------------------------
// k_lin: y = x @ W + b   (no dvis here -- applied later where Dv is known)
// ---------------------------------------------------------------------------
__global__ __launch_bounds__(256) void k_lin(const float* __restrict__ x,
                                             const float* __restrict__ Wl,
                                             const float* __restrict__ b,
                                             float* __restrict__ y) {
    __shared__ float x_s[16 * IN_DIM];
    int tid = threadIdx.x;
    int n0 = blockIdx.x * 16;
    for (int i = tid; i < 16 * IN_DIM / 4; i += 256)
        ((float4*)x_s)[i] = ((const float4*)(x + (size_t)n0 * IN_DIM))[i];
    __syncthreads();
    int k = tid & 63;
    int rbase = tid >> 6;
    for (int pass = 0; pass < 4; ++pass) {
        int r = pass * 4 + rbase;
        float acc = b[k];
        const float* xr = x_s + r * IN_DIM;
        #pragma unroll 8
        for (int i = 0; i < IN_DIM; ++i)
            acc = fmaf(xr[i], Wl[i * OUT_F + k], acc);
        y[(size_t)(n0 + r) * OUT_F + k] = acc;
    }
}

// ---------------------------------------------------------------------------
// k_zt: zT_hi/lo[64][N] = transpose(dvis * y), split into bf16 hi + lo.
// ---------------------------------------------------------------------------
__global__ __launch_bounds__(256) void k_zt(const float* __restrict__ y,
                                            const float* __restrict__ Dv_raw,
                                            unsigned short* __restrict__ zTh,
                                            unsigned short* __restrict__ zTl) {
    __shared__ unsigned short zh_s[64][264];
    __shared__ unsigned short zl_s[64][264];
    __shared__ float dvis_s[256];
    int t = threadIdx.x;
    int n0 = blockIdx.x * 256;
    dvis_s[t] = rsqrtf(fmaxf(Dv_raw[n0 + t], 1e-6f));
    __syncthreads();
    int c = t & 15, rp = t >> 4;
    for (int it = 0; it < 16; ++it) {
        int r = it * 16 + rp;
        float4 v = ((const float4*)(y + (size_t)(n0 + r) * OUT_F))[c];
        float dvs = dvis_s[r];
        float zv[4] = { v.x * dvs, v.y * dvs, v.z * dvs, v.w * dvs };
        #pragma unroll
        for (int j = 0; j < 4; ++j) {
            unsigned short hi = f2bf_rne(zv[j]);
            float lo = zv[j] - bf2f(hi);
            zh_s[4 * c + j][r] = hi;
            zl_s[4 * c + j][r] = f2bf_rne(lo);
        }
    }
    __syncthreads();
    int lane = t & 63, wv = t >> 6;
    for (int i = 0; i < 16; ++i) {
        int kk = wv * 16 + i;
        *(ushort4*)(zTh + (size_t)kk * N_NODES + n0 + lane * 4) =
            *(const ushort4*)&zh_s[kk][lane * 4];
        *(ushort4*)(zTl + (size_t)kk * N_NODES + n0 + lane * 4) =
            *(const ushort4*)&zl_s[kk][lane * 4];
    }
}

// ---------------------------------------------------------------------------
// g1: t_part[kc][m][64] = HT[m, kchunk] @ z[kchunk, 64]  (bf16 MFMA, hi+lo B)
// A-frags and B-frags load directly from global (16 B/lane, full-line).
// ---------------------------------------------------------------------------
__global__ __launch_bounds__(256) void g1(const unsigned short* __restrict__ HT,
                                          const unsigned short* __restrict__ zTh,
                                          const unsigned short* __restrict__ zTl,
                                          float* __restrict__ t_part) {
    int t = threadIdx.x;
    int lane = t & 63, wv = t >> 6;
    int l15 = lane & 15, l4 = lane >> 4;
    int m_base = blockIdx.x * 256 + wv * 64;
    int kc = blockIdx.y;
    int k_base = kc * (N_NODES / KC1);

    f32x4 acc[4][4];
    #pragma unroll
    for (int i = 0; i < 4; ++i)
        #pragma unroll
        for (int j = 0; j < 4; ++j) acc[i][j] = (f32x4){0.f, 0.f, 0.f, 0.f};

    for (int kk = 0; kk < N_NODES / KC1; kk += 32) {
        int kidx = k_base + kk + l4 * 8;
        bf16x8 a[4], bh[4], bl[4];
        #pragma unroll
        for (int fr = 0; fr < 4; ++fr)
            a[fr] = *(const bf16x8*)(HT + (size_t)(m_base + fr * 16 + l15) * N_NODES + kidx);
        #pragma unroll
        for (int fc = 0; fc < 4; ++fc) {
            bh[fc] = *(const bf16x8*)(zTh + (size_t)(fc * 16 + l15) * N_NODES + kidx);
            bl[fc] = *(const bf16x8*)(zTl + (size_t)(fc * 16 + l15) * N_NODES + kidx);
        }
        #pragma unroll
        for (int fr = 0; fr < 4; ++fr)
            #pragma unroll
            for (int fc = 0; fc < 4; ++fc) {
                acc[fr][fc] = __builtin_amdgcn_mfma_f32_16x16x32_bf16(a[fr], bh[fc], acc[fr][fc], 0, 0, 0);
                acc[fr][fc] = __builtin_amdgcn_mfma_f32_16x16x32_bf16(a[fr], bl[fc], acc[fr][fc], 0, 0, 0);
            }
    }
    float* dst = t_part + (size_t)kc * M_EDGES * OUT_F;
    #pragma unroll
    for (int fr = 0; fr < 4; ++fr)
        #pragma unroll
        for (int fc = 0; fc < 4; ++fc)
            #pragma unroll
            for (int r = 0; r < 4; ++r) {
                int row = m_base + fr * 16 + l4 * 4 + r;
                int col = fc * 16 + l15;
                dst[(size_t)row * OUT_F + col] = acc[fr][fc][r];
            }
}

// ---------------------------------------------------------------------------
// k_tt: t'[m][k] = (w[m]/max(De,1)) * sum_kc t_part;  emit transposed hi/lo.
// ---------------------------------------------------------------------------
__global__ __launch_bounds__(256) void k_tt(const float* __restrict__ t_part,
                                            const float* __restrict__ w,
                                            const float* __restrict__ De,
                                            unsigned short* __restrict__ tTh,
                                            unsigned short* __restrict__ tTl) {
    __shared__ unsigned short th_s[64][136];
    __shared__ unsigned short tl_s[64][136];
    int t = threadIdx.x;
    int m0 = blockIdx.x * 128;
    int c = t & 15, rr = t >> 4;
    for (int it = 0; it < 8; ++it) {
        int ml = it * 16 + rr;
        float4 s = {0.f, 0.f, 0.f, 0.f};
        #pragma unroll
        for (int kc = 0; kc < KC1; ++kc) {
            float4 v = ((const float4*)(t_part + ((size_t)kc * M_EDGES + m0 + ml) * OUT_F))[c];
            s.x += v.x; s.y += v.y; s.z += v.z; s.w += v.w;
        }
        float sc = w[m0 + ml] / fmaxf(De[m0 + ml], 1.0f);
        float sv[4] = { s.x * sc, s.y * sc, s.z * sc, s.w * sc };
        #pragma unroll
        for (int j = 0; j < 4; ++j) {
            unsigned short hi = f2bf_rne(sv[j]);
            th_s[4 * c + j][ml] = hi;
            tl_s[4 * c + j][ml] = f2bf_rne(sv[j] - bf2f(hi));
        }
    }
    __syncthreads();
    int lane = t & 63, wv = t >> 6;
    for (int i = 0; i < 16; ++i) {
        int kk = wv * 16 + i;
        *(ushort2*)(tTh + (size_t)kk * M_EDGES + m0 + lane * 2) =
            *(const ushort2*)&th_s[kk][lane * 2];
        *(ushort2*)(tTl + (size_t)kk * M_EDGES + m0 + lane * 2) =
            *(const ushort2*)&tl_s[kk][lane * 2];
    }
}

// ---------------------------------------------------------------------------
// g2: out_part[h][n][64] = H[n, mchunk] @ t'[mchunk, 64]
// A = H fp32 read directly, truncated to bf16 in-register (exact for 0/1).
// ---------------------------------------------------------------------------
__global__ __launch_bounds__(256) void g2(const float* __restrict__ H,
                                          const unsigned short* __restrict__ tTh,
                                          const unsigned short* __restrict__ tTl,
                                          float* __restrict__ out_part) {
    int t = threadIdx.x;
    int lane = t & 63, wv = t >> 6;
    int l15 = lane & 15, l4 = lane >> 4;
    int n_base = blockIdx.x * 256 + wv * 64;
    int h = blockIdx.y;
    int k_base = h * (M_EDGES / KC2);

    f32x4 acc[4][4];
    #pragma unroll
    for (int i = 0; i < 4; ++i)
        #pragma unroll
        for (int j = 0; j < 4; ++j) acc[i][j] = (f32x4){0.f, 0.f, 0.f, 0.f};

    for (int kk = 0; kk < M_EDGES / KC2; kk += 32) {
        int kidx = k_base + kk + l4 * 8;
        bf16x8 a[4], bh[4], bl[4];
        #pragma unroll
        for (int fr = 0; fr < 4; ++fr) {
            const float* hp = H + (size_t)(n_base + fr * 16 + l15) * M_EDGES + kidx;
            float4 q0 = *(const float4*)hp;
            float4 q1 = *(const float4*)(hp + 4);
            union { unsigned u[4]; bf16x8 v; } pk;
            pk.u[0] = __builtin_amdgcn_perm(__float_as_uint(q0.y), __float_as_uint(q0.x), 0x07060302u);
            pk.u[1] = __builtin_amdgcn_perm(__float_as_uint(q0.w), __float_as_uint(q0.z), 0x07060302u);
            pk.u[2] = __builtin_amdgcn_perm(__float_as_uint(q1.y), __float_as_uint(q1.x), 0x07060302u);
            pk.u[3] = __builtin_amdgcn_perm(__float_as_uint(q1.w), __float_as_uint(q1.z), 0x07060302u);
            a[fr] = pk.v;
        }
        #pragma unroll
        for (int fc = 0; fc < 4; ++fc) {
            bh[fc] = *(const bf16x8*)(tTh + (size_t)(fc * 16 + l15) * M_EDGES + kidx);
            bl[fc] = *(const bf16x8*)(tTl + (size_t)(fc * 16 + l15) * M_EDGES + kidx);
        }
        #pragma unroll
        for (int fr = 0; fr < 4; ++fr)
            #pragma unroll
            for (int fc = 0; fc < 4; ++fc) {
                acc[fr][fc] = __builtin_amdgcn_mfma_f32_16x16x32_bf16(a[fr], bh[fc], acc[fr][fc], 0, 0, 0);
                acc[fr][fc] = __builtin_amdgcn_mfma_f32_16x16x32_bf16(a[fr], bl[fc], acc[fr][fc], 0, 0, 0);
            }
    }
    float* dst = out_part + (size_t)h * N_NODES * OUT_F;
    #pragma unroll
    for (int fr = 0; fr < 4; ++fr)
        #pragma unroll
        for (int fc = 0; fc < 4; ++fc)
            #pragma unroll
            for (int r = 0; r < 4; ++r) {
                int row = n_base + fr * 16 + l4 * 4 + r;
                int col = fc * 16 + l15;
                dst[(size_t)row * OUT_F + col] = acc[fr][fc][r];
            }
}

// ---------------------------------------------------------------------------
// k_fin: out = dvis * sum_h out_part[h]
// ---------------------------------------------------------------------------
__global__ __launch_bounds__(256) void k_fin(const float* __restrict__ out_part,
                                             const float* __restrict__ Dv_raw,
                                             float* __restrict__ out) {
    int i4 = blockIdx.x * 256 + threadIdx.x;          // float4 index
    int n = i4 >> 4;
    float4 s = {0.f, 0.f, 0.f, 0.f};
    #pragma unroll
    for (int h = 0; h < KC2; ++h) {
        float4 v = ((const float4*)(out_part + (size_t)h * N_NODES * OUT_F))[i4];
        s.x += v.x; s.y += v.y; s.z += v.z; s.w += v.w;
    }
    float dvis = rsqrtf(fmaxf(Dv_raw[n], 1e-6f));
    float4 r = { s.x * dvis, s.y * dvis, s.z * dvis, s.w * dvis };
    ((float4*)out)[i4] = r;
}

// ---------------------------------------------------------------------------
extern "C" void kernel_launch(void* const* d_in, const int* in_sizes, int n_in,
                              void* d_out, int out_size, void* d_ws, size_t ws_size,
                              hipStream_t stream) {
    const float* x  = (const float*)d_in[0];
    const float* H  = (const float*)d_in[1];
    const float* w  = (const float*)d_in[2];
    const float* Wl = (const float*)d_in[3];
    const float* bl = (const float*)d_in[4];
    float* out = (float*)d_out;

    // workspace layout (~623 MB)
    float* y      = (float*)d_ws;                                    // N*64
    float* Dv_raw = y + (size_t)N_NODES * OUT_F;                     // N
    float* De     = Dv_raw + N_NODES;                                // M
    float* t_part = De + M_EDGES;                                    // KC1*M*64
    float* o_part = t_part + (size_t)KC1 * M_EDGES * OUT_F;          // KC2*N*64
    unsigned short* HT  = (unsigned short*)(o_part + (size_t)KC2 * N_NODES * OUT_F);
    unsigned short* zTh = HT + (size_t)M_EDGES * N_NODES;
    unsigned short* zTl = zTh + (size_t)OUT_F * N_NODES;
    unsigned short* tTh = zTl + (size_t)OUT_F * N_NODES;
    unsigned short* tTl = tTh + (size_t)OUT_F * M_EDGES;

    hipMemsetAsync(Dv_raw, 0, (N_NODES + M_EDGES) * sizeof(float), stream);

    k_prep<<<dim3(N_NODES / 256, M_EDGES / 128), dim3(256), 0, stream>>>(H, w, HT, Dv_raw, De);
    k_lin <<<dim3(N_NODES / 16),                 dim3(256), 0, stream>>>(x, Wl, bl, y);
    k_zt  <<<dim3(N_NODES / 256),                dim3(256), 0, stream>>>(y, Dv_raw, zTh, zTl);
    g1    <<<dim3(M_EDGES / 256, KC1),           dim3(256), 0, stream>>>(HT, zTh, zTl, t_part);
    k_tt  <<<dim3(M_EDGES / 128),                dim3(256), 0, stream>>>(t_part, w, De, tTh, tTl);
    g2    <<<dim3(N_NODES / 256, KC2),           dim3(256), 0, stream>>>(H, tTh, tTl, o_part);
    k_fin <<<dim3(N_NODES * OUT_F / 4 / 256),    dim3(256), 0, stream>>>(o_part, Dv_raw, out);
}

// Round 3
// 2018.116 us; speedup vs baseline: 1.1506x; 1.1506x over previous
//
#include <hip/hip_runtime.h>

#define N_NODES 32768
#define M_EDGES 8192
#define IN_DIM  256
#define OUT_F   64

#define KC1 16   // GEMM1 K-split chunks (n-dim)
#define KC2 4    // GEMM2 K-split chunks (m-dim)

#define NB8 (N_NODES / 8)    // HTb row pitch in bytes (4096)
#define MB8 (M_EDGES / 8)    // Hb  row pitch in bytes (1024)

typedef __attribute__((ext_vector_type(8))) short  bf16x8;
typedef __attribute__((ext_vector_type(4))) float  f32x4;

__device__ __forceinline__ unsigned short f2bf_rne(float f) {
    unsigned u = __float_as_uint(f);
    unsigned r = (u + 0x7FFFu + ((u >> 16) & 1u)) >> 16;
    return (unsigned short)r;
}
__device__ __forceinline__ float bf2f(unsigned short h) {
    return __uint_as_float(((unsigned)h) << 16);
}

// ---------------------------------------------------------------------------
// k_prep: the single full H read (1.07 GB). Emits bit-packed HTb (33.5 MB),
// Dv partials, De partials. 4-deep load batching keeps issue rate BW-bound.
// No bf16 HT write anymore (that was 0.54 GB of the R2 bill).
// ---------------------------------------------------------------------------
__global__ __launch_bounds__(256) void k_prep(const float* __restrict__ H,
                                              const float* __restrict__ w,
                                              unsigned char* __restrict__ HTb,
                                              float* __restrict__ Dv_raw,
                                              float* __restrict__ De) {
    __shared__ unsigned short ht_s[128][264];   // 0/1 flags, [m][n] in-tile
    __shared__ float w_s[128];
    __shared__ float de_s[128];
    int t = threadIdx.x;
    int n0 = blockIdx.x * 256;
    int m0 = blockIdx.y * 128;
    if (t < 128) { w_s[t] = w[m0 + t]; de_s[t] = 0.f; }
    __syncthreads();

    int c  = t & 31;          // float4 column within 128-wide m tile
    int rp = t >> 5;          // row phase 0..7
    float de0 = 0.f, de1 = 0.f, de2 = 0.f, de3 = 0.f;
    for (int it = 0; it < 8; ++it) {
        float4 h[4];
        #pragma unroll
        for (int q = 0; q < 4; ++q) {
            int r = it * 32 + q * 8 + rp;
            h[q] = ((const float4*)(H + (size_t)(n0 + r) * M_EDGES + m0))[c];
        }
        #pragma unroll
        for (int q = 0; q < 4; ++q) {
            int r = it * 32 + q * 8 + rp;
            float4 hv = h[q];
            int mb = 4 * c;
            ht_s[mb + 0][r] = (unsigned short)(hv.x != 0.f);
            ht_s[mb + 1][r] = (unsigned short)(hv.y != 0.f);
            ht_s[mb + 2][r] = (unsigned short)(hv.z != 0.f);
            ht_s[mb + 3][r] = (unsigned short)(hv.w != 0.f);
            float dp = hv.x * w_s[mb] + hv.y * w_s[mb + 1]
                     + hv.z * w_s[mb + 2] + hv.w * w_s[mb + 3];
            dp += __shfl_xor(dp, 1, 64);  dp += __shfl_xor(dp, 2, 64);
            dp += __shfl_xor(dp, 4, 64);  dp += __shfl_xor(dp, 8, 64);
            dp += __shfl_xor(dp, 16, 64);
            if (c == 0) atomicAdd(&Dv_raw[n0 + r], dp);
            de0 += hv.x; de1 += hv.y; de2 += hv.z; de3 += hv.w;
        }
    }
    atomicAdd(&de_s[4 * c + 0], de0);
    atomicAdd(&de_s[4 * c + 1], de1);
    atomicAdd(&de_s[4 * c + 2], de2);
    atomicAdd(&de_s[4 * c + 3], de3);
    __syncthreads();
    if (t < 128) atomicAdd(&De[m0 + t], de_s[t]);

    // bit-pack write-out: HTb[m] byte (n0/8 + nb), bit j = H[n0+8nb+j][m]
    int lane = t & 63, wv = t >> 6;
    int half = lane >> 5;         // which row of the pair
    int nb   = lane & 31;         // byte index within 32-byte row chunk
    for (int i = 0; i < 16; ++i) {
        int ml = wv * 32 + i * 2 + half;
        const unsigned short* rp2 = &ht_s[ml][nb * 8];
        unsigned bbits = 0;
        #pragma unroll
        for (int j = 0; j < 8; ++j) bbits |= (unsigned)(rp2[j] != 0) << j;
        HTb[(size_t)(m0 + ml) * NB8 + (n0 >> 3) + nb] = (unsigned char)bbits;
    }
}

// ---------------------------------------------------------------------------
// k_bt: ballot bit-transpose HTb -> Hb. One wave per 64m x 32n bit-tile:
// lane l holds 32 n-bits of row m0+l; ballot over bit b gives the 64 m-bits
// of Hb row n0+b. All traffic L3-resident (33.5 MB each way).
// ---------------------------------------------------------------------------
__global__ __launch_bounds__(256) void k_bt(const unsigned char* __restrict__ HTb,
                                            unsigned char* __restrict__ Hb) {
    int lane = threadIdx.x & 63;
    int wv   = threadIdx.x >> 6;
    int id = blockIdx.x * 4 + wv;
    int mt = id >> 10;                      // N/32 = 1024 n-tiles per m-strip
    int nt = id & 1023;
    int m0 = mt * 64, n0 = nt * 32;
    unsigned u = *(const unsigned*)(HTb + (size_t)(m0 + lane) * NB8 + (n0 >> 3));
    unsigned long long acc = 0;
    #pragma unroll
    for (int b = 0; b < 32; ++b) {
        unsigned long long bal = __ballot((u >> b) & 1u);
        acc = (lane == b) ? bal : acc;
    }
    if (lane < 32)
        *(unsigned long long*)(Hb + (size_t)(n0 + lane) * MB8 + (m0 >> 3)) = acc;
}

// ---------------------------------------------------------------------------
// k_lin: y = x @ W + b
// ---------------------------------------------------------------------------
__global__ __launch_bounds__(256) void k_lin(const float* __restrict__ x,
                                             const float* __restrict__ Wl,
                                             const float* __restrict__ b,
                                             float* __restrict__ y) {
    __shared__ float x_s[16 * IN_DIM];
    int tid = threadIdx.x;
    int n0 = blockIdx.x * 16;
    for (int i = tid; i < 16 * IN_DIM / 4; i += 256)
        ((float4*)x_s)[i] = ((const float4*)(x + (size_t)n0 * IN_DIM))[i];
    __syncthreads();
    int k = tid & 63;
    int rbase = tid >> 6;
    for (int pass = 0; pass < 4; ++pass) {
        int r = pass * 4 + rbase;
        float acc = b[k];
        const float* xr = x_s + r * IN_DIM;
        #pragma unroll 8
        for (int i = 0; i < IN_DIM; ++i)
            acc = fmaf(xr[i], Wl[i * OUT_F + k], acc);
        y[(size_t)(n0 + r) * OUT_F + k] = acc;
    }
}

// ---------------------------------------------------------------------------
// k_zt: zT_hi/lo[64][N] = transpose(dvis * y), split into bf16 hi + lo.
// ---------------------------------------------------------------------------
__global__ __launch_bounds__(256) void k_zt(const float* __restrict__ y,
                                            const float* __restrict__ Dv_raw,
                                            unsigned short* __restrict__ zTh,
                                            unsigned short* __restrict__ zTl) {
    __shared__ unsigned short zh_s[64][264];
    __shared__ unsigned short zl_s[64][264];
    __shared__ float dvis_s[256];
    int t = threadIdx.x;
    int n0 = blockIdx.x * 256;
    dvis_s[t] = rsqrtf(fmaxf(Dv_raw[n0 + t], 1e-6f));
    __syncthreads();
    int c = t & 15, rp = t >> 4;
    for (int it = 0; it < 16; ++it) {
        int r = it * 16 + rp;
        float4 v = ((const float4*)(y + (size_t)(n0 + r) * OUT_F))[c];
        float dvs = dvis_s[r];
        float zv[4] = { v.x * dvs, v.y * dvs, v.z * dvs, v.w * dvs };
        #pragma unroll
        for (int j = 0; j < 4; ++j) {
            unsigned short hi = f2bf_rne(zv[j]);
            float lo = zv[j] - bf2f(hi);
            zh_s[4 * c + j][r] = hi;
            zl_s[4 * c + j][r] = f2bf_rne(lo);
        }
    }
    __syncthreads();
    int lane = t & 63, wv = t >> 6;
    for (int i = 0; i < 16; ++i) {
        int kk = wv * 16 + i;
        *(ushort4*)(zTh + (size_t)kk * N_NODES + n0 + lane * 4) =
            *(const ushort4*)&zh_s[kk][lane * 4];
        *(ushort4*)(zTl + (size_t)kk * N_NODES + n0 + lane * 4) =
            *(const ushort4*)&zl_s[kk][lane * 4];
    }
}

// ---------------------------------------------------------------------------
// g1: t_part[kc][m][64] = HT[m, kchunk] @ z[kchunk, 64]
// A from bit-packed HTb: 1 dword (L1-resident row lines) + LUT ds_read_b128.
// ---------------------------------------------------------------------------
__global__ __launch_bounds__(256) void g1(const unsigned char* __restrict__ HTb,
                                          const unsigned short* __restrict__ zTh,
                                          const unsigned short* __restrict__ zTl,
                                          float* __restrict__ t_part) {
    __shared__ unsigned short lut[256][8];   // byte -> 8 bf16 {0,1}
    int t = threadIdx.x;
    #pragma unroll
    for (int j = 0; j < 8; ++j)
        lut[t][j] = ((t >> j) & 1) ? 0x3F80 : 0;
    __syncthreads();

    int lane = t & 63, wv = t >> 6;
    int l15 = lane & 15, l4 = lane >> 4;
    int m_base = blockIdx.x * 256 + wv * 64;
    int kc = blockIdx.y;
    int k_base = kc * (N_NODES / KC1);

    f32x4 acc[4][4];
    #pragma unroll
    for (int i = 0; i < 4; ++i)
        #pragma unroll
        for (int j = 0; j < 4; ++j) acc[i][j] = (f32x4){0.f, 0.f, 0.f, 0.f};

    const unsigned* arow[4];
    #pragma unroll
    for (int fr = 0; fr < 4; ++fr)
        arow[fr] = (const unsigned*)(HTb + (size_t)(m_base + fr * 16 + l15) * NB8);

    for (int kk = 0; kk < N_NODES / KC1; kk += 32) {
        int kd   = (k_base + kk) >> 5;          // dword index in bit-row
        int kidx = k_base + kk + l4 * 8;
        bf16x8 a[4], bh[4], bl[4];
        #pragma unroll
        for (int fr = 0; fr < 4; ++fr) {
            unsigned u  = arow[fr][kd];
            unsigned by = (u >> (l4 * 8)) & 255u;
            a[fr] = *(const bf16x8*)&lut[by][0];
        }
        #pragma unroll
        for (int fc = 0; fc < 4; ++fc) {
            bh[fc] = *(const bf16x8*)(zTh + (size_t)(fc * 16 + l15) * N_NODES + kidx);
            bl[fc] = *(const bf16x8*)(zTl + (size_t)(fc * 16 + l15) * N_NODES + kidx);
        }
        #pragma unroll
        for (int fr = 0; fr < 4; ++fr)
            #pragma unroll
            for (int fc = 0; fc < 4; ++fc) {
                acc[fr][fc] = __builtin_amdgcn_mfma_f32_16x16x32_bf16(a[fr], bh[fc], acc[fr][fc], 0, 0, 0);
                acc[fr][fc] = __builtin_amdgcn_mfma_f32_16x16x32_bf16(a[fr], bl[fc], acc[fr][fc], 0, 0, 0);
            }
    }
    float* dst = t_part + (size_t)kc * M_EDGES * OUT_F;
    #pragma unroll
    for (int fr = 0; fr < 4; ++fr)
        #pragma unroll
        for (int fc = 0; fc < 4; ++fc)
            #pragma unroll
            for (int r = 0; r < 4; ++r) {
                int row = m_base + fr * 16 + l4 * 4 + r;
                int col = fc * 16 + l15;
                dst[(size_t)row * OUT_F + col] = acc[fr][fc][r];
            }
}

// ---------------------------------------------------------------------------
// k_tt: t'[m][k] = (w[m]/max(De,1)) * sum_kc t_part;  emit transposed hi/lo.
// ---------------------------------------------------------------------------
__global__ __launch_bounds__(256) void k_tt(const float* __restrict__ t_part,
                                            const float* __restrict__ w,
                                            const float* __restrict__ De,
                                            unsigned short* __restrict__ tTh,
                                            unsigned short* __restrict__ tTl) {
    __shared__ unsigned short th_s[64][136];
    __shared__ unsigned short tl_s[64][136];
    int t = threadIdx.x;
    int m0 = blockIdx.x * 128;
    int c = t & 15, rr = t >> 4;
    for (int it = 0; it < 8; ++it) {
        int ml = it * 16 + rr;
        float4 s = {0.f, 0.f, 0.f, 0.f};
        #pragma unroll
        for (int kc = 0; kc < KC1; ++kc) {
            float4 v = ((const float4*)(t_part + ((size_t)kc * M_EDGES + m0 + ml) * OUT_F))[c];
            s.x += v.x; s.y += v.y; s.z += v.z; s.w += v.w;
        }
        float sc = w[m0 + ml] / fmaxf(De[m0 + ml], 1.0f);
        float sv[4] = { s.x * sc, s.y * sc, s.z * sc, s.w * sc };
        #pragma unroll
        for (int j = 0; j < 4; ++j) {
            unsigned short hi = f2bf_rne(sv[j]);
            th_s[4 * c + j][ml] = hi;
            tl_s[4 * c + j][ml] = f2bf_rne(sv[j] - bf2f(hi));
        }
    }
    __syncthreads();
    int lane = t & 63, wv = t >> 6;
    for (int i = 0; i < 16; ++i) {
        int kk = wv * 16 + i;
        *(ushort2*)(tTh + (size_t)kk * M_EDGES + m0 + lane * 2) =
            *(const ushort2*)&th_s[kk][lane * 2];
        *(ushort2*)(tTl + (size_t)kk * M_EDGES + m0 + lane * 2) =
            *(const ushort2*)&tl_s[kk][lane * 2];
    }
}

// ---------------------------------------------------------------------------
// g2: out_part[h][n][64] = H[n, mchunk] @ t'[mchunk, 64]; A from Hb bits.
// ---------------------------------------------------------------------------
__global__ __launch_bounds__(256) void g2(const unsigned char* __restrict__ Hb,
                                          const unsigned short* __restrict__ tTh,
                                          const unsigned short* __restrict__ tTl,
                                          float* __restrict__ out_part) {
    __shared__ unsigned short lut[256][8];
    int t = threadIdx.x;
    #pragma unroll
    for (int j = 0; j < 8; ++j)
        lut[t][j] = ((t >> j) & 1) ? 0x3F80 : 0;
    __syncthreads();

    int lane = t & 63, wv = t >> 6;
    int l15 = lane & 15, l4 = lane >> 4;
    int n_base = blockIdx.x * 256 + wv * 64;
    int h = blockIdx.y;
    int k_base = h * (M_EDGES / KC2);

    f32x4 acc[4][4];
    #pragma unroll
    for (int i = 0; i < 4; ++i)
        #pragma unroll
        for (int j = 0; j < 4; ++j) acc[i][j] = (f32x4){0.f, 0.f, 0.f, 0.f};

    const unsigned* arow[4];
    #pragma unroll
    for (int fr = 0; fr < 4; ++fr)
        arow[fr] = (const unsigned*)(Hb + (size_t)(n_base + fr * 16 + l15) * MB8);

    for (int kk = 0; kk < M_EDGES / KC2; kk += 32) {
        int kd   = (k_base + kk) >> 5;
        int kidx = k_base + kk + l4 * 8;
        bf16x8 a[4], bh[4], bl[4];
        #pragma unroll
        for (int fr = 0; fr < 4; ++fr) {
            unsigned u  = arow[fr][kd];
            unsigned by = (u >> (l4 * 8)) & 255u;
            a[fr] = *(const bf16x8*)&lut[by][0];
        }
        #pragma unroll
        for (int fc = 0; fc < 4; ++fc) {
            bh[fc] = *(const bf16x8*)(tTh + (size_t)(fc * 16 + l15) * M_EDGES + kidx);
            bl[fc] = *(const bf16x8*)(tTl + (size_t)(fc * 16 + l15) * M_EDGES + kidx);
        }
        #pragma unroll
        for (int fr = 0; fr < 4; ++fr)
            #pragma unroll
            for (int fc = 0; fc < 4; ++fc) {
                acc[fr][fc] = __builtin_amdgcn_mfma_f32_16x16x32_bf16(a[fr], bh[fc], acc[fr][fc], 0, 0, 0);
                acc[fr][fc] = __builtin_amdgcn_mfma_f32_16x16x32_bf16(a[fr], bl[fc], acc[fr][fc], 0, 0, 0);
            }
    }
    float* dst = out_part + (size_t)h * N_NODES * OUT_F;
    #pragma unroll
    for (int fr = 0; fr < 4; ++fr)
        #pragma unroll
        for (int fc = 0; fc < 4; ++fc)
            #pragma unroll
            for (int r = 0; r < 4; ++r) {
                int row = n_base + fr * 16 + l4 * 4 + r;
                int col = fc * 16 + l15;
                dst[(size_t)row * OUT_F + col] = acc[fr][fc][r];
            }
}

// ---------------------------------------------------------------------------
// k_fin: out = dvis * sum_h out_part[h]
// ---------------------------------------------------------------------------
__global__ __launch_bounds__(256) void k_fin(const float* __restrict__ out_part,
                                             const float* __restrict__ Dv_raw,
                                             float* __restrict__ out) {
    int i4 = blockIdx.x * 256 + threadIdx.x;
    int n = i4 >> 4;
    float4 s = {0.f, 0.f, 0.f, 0.f};
    #pragma unroll
    for (int h = 0; h < KC2; ++h) {
        float4 v = ((const float4*)(out_part + (size_t)h * N_NODES * OUT_F))[i4];
        s.x += v.x; s.y += v.y; s.z += v.z; s.w += v.w;
    }
    float dvis = rsqrtf(fmaxf(Dv_raw[n], 1e-6f));
    float4 r = { s.x * dvis, s.y * dvis, s.z * dvis, s.w * dvis };
    ((float4*)out)[i4] = r;
}

// ---------------------------------------------------------------------------
extern "C" void kernel_launch(void* const* d_in, const int* in_sizes, int n_in,
                              void* d_out, int out_size, void* d_ws, size_t ws_size,
                              hipStream_t stream) {
    const float* x  = (const float*)d_in[0];
    const float* H  = (const float*)d_in[1];
    const float* w  = (const float*)d_in[2];
    const float* Wl = (const float*)d_in[3];
    const float* bl = (const float*)d_in[4];
    float* out = (float*)d_out;

    float* y      = (float*)d_ws;                                    // N*64
    float* Dv_raw = y + (size_t)N_NODES * OUT_F;                     // N
    float* De     = Dv_raw + N_NODES;                                // M
    float* t_part = De + M_EDGES;                                    // KC1*M*64
    float* o_part = t_part + (size_t)KC1 * M_EDGES * OUT_F;          // KC2*N*64
    unsigned short* zTh = (unsigned short*)(o_part + (size_t)KC2 * N_NODES * OUT_F);
    unsigned short* zTl = zTh + (size_t)OUT_F * N_NODES;
    unsigned short* tTh = zTl + (size_t)OUT_F * N_NODES;
    unsigned short* tTl = tTh + (size_t)OUT_F * M_EDGES;
    unsigned char*  HTb = (unsigned char*)(tTl + (size_t)OUT_F * M_EDGES);
    unsigned char*  Hb  = HTb + (size_t)M_EDGES * NB8;

    hipMemsetAsync(Dv_raw, 0, (N_NODES + M_EDGES) * sizeof(float), stream);

    k_prep<<<dim3(N_NODES / 256, M_EDGES / 128), dim3(256), 0, stream>>>(H, w, HTb, Dv_raw, De);
    k_bt  <<<dim3((M_EDGES / 64) * (N_NODES / 32) / 4), dim3(256), 0, stream>>>(HTb, Hb);
    k_lin <<<dim3(N_NODES / 16),                 dim3(256), 0, stream>>>(x, Wl, bl, y);
    k_zt  <<<dim3(N_NODES / 256),                dim3(256), 0, stream>>>(y, Dv_raw, zTh, zTl);
    g1    <<<dim3(M_EDGES / 256, KC1),           dim3(256), 0, stream>>>(HTb, zTh, zTl, t_part);
    k_tt  <<<dim3(M_EDGES / 128),                dim3(256), 0, stream>>>(t_part, w, De, tTh, tTl);
    g2    <<<dim3(N_NODES / 256, KC2),           dim3(256), 0, stream>>>(Hb, tTh, tTl, o_part);
    k_fin <<<dim3(N_NODES * OUT_F / 4 / 256),    dim3(256), 0, stream>>>(o_part, Dv_raw, out);
}

// Round 4
// 1896.845 us; speedup vs baseline: 1.2241x; 1.0639x over previous
//
#include <hip/hip_runtime.h>

#define N_NODES 32768
#define M_EDGES 8192
#define IN_DIM  256
#define OUT_F   64

#define KC1 16   // GEMM1 K-split chunks (n-dim)
#define KC2 4    // GEMM2 K-split chunks (m-dim)

#define NB8 (N_NODES / 8)    // HTb row pitch in bytes (4096)
#define MB8 (M_EDGES / 8)    // Hb  row pitch in bytes (1024)

typedef __attribute__((ext_vector_type(8))) short  bf16x8;
typedef __attribute__((ext_vector_type(4))) float  f32x4;

__device__ __forceinline__ unsigned short f2bf_rne(float f) {
    unsigned u = __float_as_uint(f);
    unsigned r = (u + 0x7FFFu + ((u >> 16) & 1u)) >> 16;
    return (unsigned short)r;
}
__device__ __forceinline__ float bf2f(unsigned short h) {
    return __uint_as_float(((unsigned)h) << 16);
}

// pi-map: Hb dword D (= 8i + 2q + h), bit b  <->  m = 256i + 128h + 4b + q
// (q = float4 component, h = wave half, b = ballot lane within half)

// ---------------------------------------------------------------------------
// k_pack: the single full H read (1.07 GB) -> Hb bits via ballot packing.
// Per 1 KB wave-load: 1 load + 4 ballots + ~10 select/store ops (~0.02
// instr/B, vs R3 k_prep's ~1.3 instr/B which was the hidden ~1.1 ms sink).
// One wave per row; 4-deep load batching; no LDS, no atomics, no shfl.
// ---------------------------------------------------------------------------
__global__ __launch_bounds__(256) void k_pack(const float* __restrict__ H,
                                              unsigned char* __restrict__ Hb) {
    int lane = threadIdx.x & 63;
    int wv   = threadIdx.x >> 6;
    int n = blockIdx.x * 4 + wv;
    const float4* Hrow = (const float4*)(H + (size_t)n * M_EDGES);
    unsigned* hb_row = (unsigned*)(Hb + (size_t)n * MB8);

    for (int i0 = 0; i0 < 32; i0 += 4) {
        float4 h0 = Hrow[(i0 + 0) * 64 + lane];
        float4 h1 = Hrow[(i0 + 1) * 64 + lane];
        float4 h2 = Hrow[(i0 + 2) * 64 + lane];
        float4 h3 = Hrow[(i0 + 3) * 64 + lane];
        #define PACK1(hv, ii)                                                  \
        {                                                                      \
            unsigned long long B0 = __ballot(hv.x != 0.f);                     \
            unsigned long long B1 = __ballot(hv.y != 0.f);                     \
            unsigned long long B2 = __ballot(hv.z != 0.f);                     \
            unsigned long long B3 = __ballot(hv.w != 0.f);                     \
            unsigned long long s01 = (lane & 2) ? B1 : B0;                     \
            unsigned long long s23 = (lane & 2) ? B3 : B2;                     \
            unsigned long long ss  = (lane & 4) ? s23 : s01;                   \
            unsigned v = (lane & 1) ? (unsigned)(ss >> 32) : (unsigned)ss;     \
            if (lane < 8) hb_row[(ii) * 8 + lane] = v;                         \
        }
        PACK1(h0, i0 + 0)
        PACK1(h1, i0 + 1)
        PACK1(h2, i0 + 2)
        PACK1(h3, i0 + 3)
        #undef PACK1
    }
}

// ---------------------------------------------------------------------------
// k_bt: ballot bit-transpose Hb -> HTb, decoding the pi-map in its output
// row index (rows were already scattered, so the permutation is free).
// HTb rows are true-m, bits in true-n order -> g1 stays unchanged.
// ---------------------------------------------------------------------------
__global__ __launch_bounds__(256) void k_bt(const unsigned char* __restrict__ Hb,
                                            unsigned char* __restrict__ HTb) {
    int lane = threadIdx.x & 63;
    int wv   = threadIdx.x >> 6;
    int id = blockIdx.x * 4 + wv;
    int D  = id & 255;                       // dword index within Hb row
    int n0 = (id >> 8) * 64;
    unsigned u = *(const unsigned*)(Hb + (size_t)(n0 + lane) * MB8 + D * 4);
    int mbase = ((D >> 3) << 8) + ((D & 1) << 7) + ((D >> 1) & 3);
    unsigned long long acc = 0;
    #pragma unroll
    for (int b = 0; b < 32; ++b) {
        unsigned long long bal = __ballot((u >> b) & 1u);
        acc = (lane == b) ? bal : acc;
    }
    if (lane < 32)
        *(unsigned long long*)(HTb + (size_t)(mbase + 4 * lane) * NB8 + (n0 >> 3)) = acc;
}

// ---------------------------------------------------------------------------
// k_dv: Dv[n] = sum_m w[m] * H[n][m] from Hb bits (ffs loop, ~0.3 set
// bits/dword); w gathers are L2-hot. One wave per row.
// ---------------------------------------------------------------------------
__global__ __launch_bounds__(256) void k_dv(const unsigned char* __restrict__ Hb,
                                            const float* __restrict__ w,
                                            float* __restrict__ Dv_raw) {
    int lane = threadIdx.x & 63;
    int wv   = threadIdx.x >> 6;
    int n = blockIdx.x * 4 + wv;
    const uint4* row = (const uint4*)(Hb + (size_t)n * MB8);
    uint4 u4 = row[lane];
    float dv = 0.f;
    #define DVD(uu, dd)                                                        \
    {                                                                          \
        unsigned u = (uu);                                                     \
        int D = lane * 4 + (dd);                                               \
        int base = ((D >> 3) << 8) + ((D & 1) << 7) + ((D >> 1) & 3);          \
        while (u) { int p = __ffs(u) - 1; dv += w[base + 4 * p]; u &= u - 1; } \
    }
    DVD(u4.x, 0) DVD(u4.y, 1) DVD(u4.z, 2) DVD(u4.w, 3)
    #undef DVD
    for (int off = 32; off; off >>= 1) dv += __shfl_down(dv, off, 64);
    if (lane == 0) Dv_raw[n] = dv;
}

// ---------------------------------------------------------------------------
// k_lin: y = x @ W + b   (unchanged from R3)
// ---------------------------------------------------------------------------
__global__ __launch_bounds__(256) void k_lin(const float* __restrict__ x,
                                             const float* __restrict__ Wl,
                                             const float* __restrict__ b,
                                             float* __restrict__ y) {
    __shared__ float x_s[16 * IN_DIM];
    int tid = threadIdx.x;
    int n0 = blockIdx.x * 16;
    for (int i = tid; i < 16 * IN_DIM / 4; i += 256)
        ((float4*)x_s)[i] = ((const float4*)(x + (size_t)n0 * IN_DIM))[i];
    __syncthreads();
    int k = tid & 63;
    int rbase = tid >> 6;
    for (int pass = 0; pass < 4; ++pass) {
        int r = pass * 4 + rbase;
        float acc = b[k];
        const float* xr = x_s + r * IN_DIM;
        #pragma unroll 8
        for (int i = 0; i < IN_DIM; ++i)
            acc = fmaf(xr[i], Wl[i * OUT_F + k], acc);
        y[(size_t)(n0 + r) * OUT_F + k] = acc;
    }
}

// ---------------------------------------------------------------------------
// k_zt: zT_hi/lo[64][N] = transpose(dvis * y), bf16 hi + lo (unchanged).
// Columns stay in true-n order (HTb bits are true-n).
// ---------------------------------------------------------------------------
__global__ __launch_bounds__(256) void k_zt(const float* __restrict__ y,
                                            const float* __restrict__ Dv_raw,
                                            unsigned short* __restrict__ zTh,
                                            unsigned short* __restrict__ zTl) {
    __shared__ unsigned short zh_s[64][264];
    __shared__ unsigned short zl_s[64][264];
    __shared__ float dvis_s[256];
    int t = threadIdx.x;
    int n0 = blockIdx.x * 256;
    dvis_s[t] = rsqrtf(fmaxf(Dv_raw[n0 + t], 1e-6f));
    __syncthreads();
    int c = t & 15, rp = t >> 4;
    for (int it = 0; it < 16; ++it) {
        int r = it * 16 + rp;
        float4 v = ((const float4*)(y + (size_t)(n0 + r) * OUT_F))[c];
        float dvs = dvis_s[r];
        float zv[4] = { v.x * dvs, v.y * dvs, v.z * dvs, v.w * dvs };
        #pragma unroll
        for (int j = 0; j < 4; ++j) {
            unsigned short hi = f2bf_rne(zv[j]);
            float lo = zv[j] - bf2f(hi);
            zh_s[4 * c + j][r] = hi;
            zl_s[4 * c + j][r] = f2bf_rne(lo);
        }
    }
    __syncthreads();
    int lane = t & 63, wv = t >> 6;
    for (int i = 0; i < 16; ++i) {
        int kk = wv * 16 + i;
        *(ushort4*)(zTh + (size_t)kk * N_NODES + n0 + lane * 4) =
            *(const ushort4*)&zh_s[kk][lane * 4];
        *(ushort4*)(zTl + (size_t)kk * N_NODES + n0 + lane * 4) =
            *(const ushort4*)&zl_s[kk][lane * 4];
    }
}

// ---------------------------------------------------------------------------
// g1: t_part[kc][m][64] = HT[m, kchunk] @ z[kchunk, 64]   (unchanged)
// ---------------------------------------------------------------------------
__global__ __launch_bounds__(256) void g1(const unsigned char* __restrict__ HTb,
                                          const unsigned short* __restrict__ zTh,
                                          const unsigned short* __restrict__ zTl,
                                          float* __restrict__ t_part) {
    __shared__ unsigned short lut[256][8];   // byte -> 8 bf16 {0,1}
    int t = threadIdx.x;
    #pragma unroll
    for (int j = 0; j < 8; ++j)
        lut[t][j] = ((t >> j) & 1) ? 0x3F80 : 0;
    __syncthreads();

    int lane = t & 63, wv = t >> 6;
    int l15 = lane & 15, l4 = lane >> 4;
    int m_base = blockIdx.x * 256 + wv * 64;
    int kc = blockIdx.y;
    int k_base = kc * (N_NODES / KC1);

    f32x4 acc[4][4];
    #pragma unroll
    for (int i = 0; i < 4; ++i)
        #pragma unroll
        for (int j = 0; j < 4; ++j) acc[i][j] = (f32x4){0.f, 0.f, 0.f, 0.f};

    const unsigned* arow[4];
    #pragma unroll
    for (int fr = 0; fr < 4; ++fr)
        arow[fr] = (const unsigned*)(HTb + (size_t)(m_base + fr * 16 + l15) * NB8);

    for (int kk = 0; kk < N_NODES / KC1; kk += 32) {
        int kd   = (k_base + kk) >> 5;
        int kidx = k_base + kk + l4 * 8;
        bf16x8 a[4], bh[4], bl[4];
        #pragma unroll
        for (int fr = 0; fr < 4; ++fr) {
            unsigned u  = arow[fr][kd];
            unsigned by = (u >> (l4 * 8)) & 255u;
            a[fr] = *(const bf16x8*)&lut[by][0];
        }
        #pragma unroll
        for (int fc = 0; fc < 4; ++fc) {
            bh[fc] = *(const bf16x8*)(zTh + (size_t)(fc * 16 + l15) * N_NODES + kidx);
            bl[fc] = *(const bf16x8*)(zTl + (size_t)(fc * 16 + l15) * N_NODES + kidx);
        }
        #pragma unroll
        for (int fr = 0; fr < 4; ++fr)
            #pragma unroll
            for (int fc = 0; fc < 4; ++fc) {
                acc[fr][fc] = __builtin_amdgcn_mfma_f32_16x16x32_bf16(a[fr], bh[fc], acc[fr][fc], 0, 0, 0);
                acc[fr][fc] = __builtin_amdgcn_mfma_f32_16x16x32_bf16(a[fr], bl[fc], acc[fr][fc], 0, 0, 0);
            }
    }
    float* dst = t_part + (size_t)kc * M_EDGES * OUT_F;
    #pragma unroll
    for (int fr = 0; fr < 4; ++fr)
        #pragma unroll
        for (int fc = 0; fc < 4; ++fc)
            #pragma unroll
            for (int r = 0; r < 4; ++r) {
                int row = m_base + fr * 16 + l4 * 4 + r;
                int col = fc * 16 + l15;
                dst[(size_t)row * OUT_F + col] = acc[fr][fc][r];
            }
}

// ---------------------------------------------------------------------------
// k_tt: t'[m] = (w[m]/max(De,1)) * sum_kc t_part[..m..]; De from HTb
// popcount (exact); store hi/lo bf16 to pi-permuted tT columns so g2's
// Hb-bit order pairs correctly.
// ---------------------------------------------------------------------------
__global__ __launch_bounds__(256) void k_tt(const float* __restrict__ t_part,
                                            const float* __restrict__ w,
                                            const unsigned char* __restrict__ HTb,
                                            unsigned short* __restrict__ tTh,
                                            unsigned short* __restrict__ tTl) {
    __shared__ unsigned short th_s[64][136];
    __shared__ unsigned short tl_s[64][136];
    __shared__ float de_s[128];
    int t = threadIdx.x;
    int m0 = blockIdx.x * 128;

    {   // De[m] = popcount(HTb row m); 2 threads per row
        int ml = t >> 1, hh = t & 1;
        const uint4* rp = (const uint4*)(HTb + (size_t)(m0 + ml) * NB8) + hh * 128;
        unsigned cnt = 0;
        #pragma unroll 4
        for (int i = 0; i < 128; ++i) {
            uint4 v = rp[i];
            cnt += (unsigned)(__popc(v.x) + __popc(v.y) + __popc(v.z) + __popc(v.w));
        }
        cnt += (unsigned)__shfl_xor((int)cnt, 1, 64);
        if (hh == 0) de_s[ml] = (float)cnt;
    }
    __syncthreads();

    int c = t & 15, rr = t >> 4;
    for (int it = 0; it < 8; ++it) {
        int ml = it * 16 + rr;
        float4 s = {0.f, 0.f, 0.f, 0.f};
        #pragma unroll
        for (int kc = 0; kc < KC1; ++kc) {
            float4 v = ((const float4*)(t_part + ((size_t)kc * M_EDGES + m0 + ml) * OUT_F))[c];
            s.x += v.x; s.y += v.y; s.z += v.z; s.w += v.w;
        }
        float sc = w[m0 + ml] / fmaxf(de_s[ml], 1.0f);
        float sv[4] = { s.x * sc, s.y * sc, s.z * sc, s.w * sc };
        #pragma unroll
        for (int j = 0; j < 4; ++j) {
            unsigned short hi = f2bf_rne(sv[j]);
            th_s[4 * c + j][ml] = hi;
            tl_s[4 * c + j][ml] = f2bf_rne(sv[j] - bf2f(hi));
        }
    }
    __syncthreads();
    // permuted column store: m -> R(m) = 256*(m>>8)+64*(m&3)+32*((m>>7)&1)
    //                                   +8*((m>>5)&3)+((m>>2)&7)
    for (int s = t; s < 64 * 128; s += 256) {
        int kk = s >> 7;
        int ml = s & 127;
        int m = m0 + ml;
        int R = ((m >> 8) << 8) + ((m & 3) << 6) + (((m >> 7) & 1) << 5)
              + (((m >> 5) & 3) << 3) + ((m >> 2) & 7);
        tTh[(size_t)kk * M_EDGES + R] = th_s[kk][ml];
        tTl[(size_t)kk * M_EDGES + R] = tl_s[kk][ml];
    }
}

// ---------------------------------------------------------------------------
// g2: out_part[h][n][64] = H[n, mchunk] @ t'[mchunk, 64]; A from Hb bits
// (pi-coded; tT columns pre-permuted to match). Unchanged from R3.
// ---------------------------------------------------------------------------
__global__ __launch_bounds__(256) void g2(const unsigned char* __restrict__ Hb,
                                          const unsigned short* __restrict__ tTh,
                                          const unsigned short* __restrict__ tTl,
                                          float* __restrict__ out_part) {
    __shared__ unsigned short lut[256][8];
    int t = threadIdx.x;
    #pragma unroll
    for (int j = 0; j < 8; ++j)
        lut[t][j] = ((t >> j) & 1) ? 0x3F80 : 0;
    __syncthreads();

    int lane = t & 63, wv = t >> 6;
    int l15 = lane & 15, l4 = lane >> 4;
    int n_base = blockIdx.x * 256 + wv * 64;
    int h = blockIdx.y;
    int k_base = h * (M_EDGES / KC2);

    f32x4 acc[4][4];
    #pragma unroll
    for (int i = 0; i < 4; ++i)
        #pragma unroll
        for (int j = 0; j < 4; ++j) acc[i][j] = (f32x4){0.f, 0.f, 0.f, 0.f};

    const unsigned* arow[4];
    #pragma unroll
    for (int fr = 0; fr < 4; ++fr)
        arow[fr] = (const unsigned*)(Hb + (size_t)(n_base + fr * 16 + l15) * MB8);

    for (int kk = 0; kk < M_EDGES / KC2; kk += 32) {
        int kd   = (k_base + kk) >> 5;
        int kidx = k_base + kk + l4 * 8;
        bf16x8 a[4], bh[4], bl[4];
        #pragma unroll
        for (int fr = 0; fr < 4; ++fr) {
            unsigned u  = arow[fr][kd];
            unsigned by = (u >> (l4 * 8)) & 255u;
            a[fr] = *(const bf16x8*)&lut[by][0];
        }
        #pragma unroll
        for (int fc = 0; fc < 4; ++fc) {
            bh[fc] = *(const bf16x8*)(tTh + (size_t)(fc * 16 + l15) * M_EDGES + kidx);
            bl[fc] = *(const bf16x8*)(tTl + (size_t)(fc * 16 + l15) * M_EDGES + kidx);
        }
        #pragma unroll
        for (int fr = 0; fr < 4; ++fr)
            #pragma unroll
            for (int fc = 0; fc < 4; ++fc) {
                acc[fr][fc] = __builtin_amdgcn_mfma_f32_16x16x32_bf16(a[fr], bh[fc], acc[fr][fc], 0, 0, 0);
                acc[fr][fc] = __builtin_amdgcn_mfma_f32_16x16x32_bf16(a[fr], bl[fc], acc[fr][fc], 0, 0, 0);
            }
    }
    float* dst = out_part + (size_t)h * N_NODES * OUT_F;
    #pragma unroll
    for (int fr = 0; fr < 4; ++fr)
        #pragma unroll
        for (int fc = 0; fc < 4; ++fc)
            #pragma unroll
            for (int r = 0; r < 4; ++r) {
                int row = n_base + fr * 16 + l4 * 4 + r;
                int col = fc * 16 + l15;
                dst[(size_t)row * OUT_F + col] = acc[fr][fc][r];
            }
}

// ---------------------------------------------------------------------------
// k_fin: out = dvis * sum_h out_part[h]   (unchanged)
// ---------------------------------------------------------------------------
__global__ __launch_bounds__(256) void k_fin(const float* __restrict__ out_part,
                                             const float* __restrict__ Dv_raw,
                                             float* __restrict__ out) {
    int i4 = blockIdx.x * 256 + threadIdx.x;
    int n = i4 >> 4;
    float4 s = {0.f, 0.f, 0.f, 0.f};
    #pragma unroll
    for (int h = 0; h < KC2; ++h) {
        float4 v = ((const float4*)(out_part + (size_t)h * N_NODES * OUT_F))[i4];
        s.x += v.x; s.y += v.y; s.z += v.z; s.w += v.w;
    }
    float dvis = rsqrtf(fmaxf(Dv_raw[n], 1e-6f));
    float4 r = { s.x * dvis, s.y * dvis, s.z * dvis, s.w * dvis };
    ((float4*)out)[i4] = r;
}

// ---------------------------------------------------------------------------
extern "C" void kernel_launch(void* const* d_in, const int* in_sizes, int n_in,
                              void* d_out, int out_size, void* d_ws, size_t ws_size,
                              hipStream_t stream) {
    const float* x  = (const float*)d_in[0];
    const float* H  = (const float*)d_in[1];
    const float* w  = (const float*)d_in[2];
    const float* Wl = (const float*)d_in[3];
    const float* bl = (const float*)d_in[4];
    float* out = (float*)d_out;

    float* y      = (float*)d_ws;                                    // N*64
    float* Dv_raw = y + (size_t)N_NODES * OUT_F;                     // N
    float* t_part = Dv_raw + N_NODES;                                // KC1*M*64
    float* o_part = t_part + (size_t)KC1 * M_EDGES * OUT_F;          // KC2*N*64
    unsigned short* zTh = (unsigned short*)(o_part + (size_t)KC2 * N_NODES * OUT_F);
    unsigned short* zTl = zTh + (size_t)OUT_F * N_NODES;
    unsigned short* tTh = zTl + (size_t)OUT_F * N_NODES;
    unsigned short* tTl = tTh + (size_t)OUT_F * M_EDGES;
    unsigned char*  Hb  = (unsigned char*)(tTl + (size_t)OUT_F * M_EDGES);
    unsigned char*  HTb = Hb + (size_t)N_NODES * MB8;

    k_pack<<<dim3(N_NODES / 4), dim3(256), 0, stream>>>(H, Hb);
    k_bt  <<<dim3((N_NODES / 64) * (M_EDGES / 32) / 4), dim3(256), 0, stream>>>(Hb, HTb);
    k_dv  <<<dim3(N_NODES / 4), dim3(256), 0, stream>>>(Hb, w, Dv_raw);
    k_lin <<<dim3(N_NODES / 16), dim3(256), 0, stream>>>(x, Wl, bl, y);
    k_zt  <<<dim3(N_NODES / 256), dim3(256), 0, stream>>>(y, Dv_raw, zTh, zTl);
    g1    <<<dim3(M_EDGES / 256, KC1), dim3(256), 0, stream>>>(HTb, zTh, zTl, t_part);
    k_tt  <<<dim3(M_EDGES / 128), dim3(256), 0, stream>>>(t_part, w, HTb, tTh, tTl);
    g2    <<<dim3(N_NODES / 256, KC2), dim3(256), 0, stream>>>(Hb, tTh, tTl, o_part);
    k_fin <<<dim3(N_NODES * OUT_F / 4 / 256), dim3(256), 0, stream>>>(o_part, Dv_raw, out);
}